// Round 2
// baseline (72.300 us; speedup 1.0000x reference)
//
#include <hip/hip_runtime.h>
#include <math.h>

// Chamfer one-sided NN distance sum. N = M = 16384, D = 3, fp32 -> scalar fp32.
//
// R17: shrink the non-fill portion. Counters show the harness's 256MiB ws
// poison-fill (~39.6us @ 85% HBM peak) dominates dur_us; our 3 kernels +
// gaps = ~31us vs a ~8-10us model. Changes vs R16 (all bit-identical math):
//   1. aexp eliminated: sweep builds its A-fragment inline from a[] with the
//      R8/R0-verified split-bf16 recipe (once per wave, ~30 VALU ops).
//      Pack kernel is now B-only (16384 pts -> 256KB compact operand).
//   2. Sweep inner loop processes 4 tiles per iteration with all 4
//      global_load_dwordx4 issued before any consume -> staggered
//      vmcnt(3/2/1/0) waits instead of a ~200cy L2-latency stall per pair
//      (only 4 waves/SIMD available to hide it).
//   3. Reduce kernel byte-identical to R15/R16 -> bit-exact output sum
//      (absmax 0.0 preserved; min is order-independent).
//
// MFMA formulation (R8, absmax 0.0 verified): d2(i,j) = |a|^2+|b|^2-2a.b via
// split-bf16, one v_mfma_f32_32x32x16_bf16 per 32x32 tile:
//   A[i][k] = [ahx,ahy,ahz, ahx,ahy,ahz, alx,aly,alz, alx,aly,alz, a2h,a2l,1,1]
//   B[j][k] = [-2bh(3),-2bl(3), -2bh(3),-2bl(3), 1,1, b2h,b2l]
// B stored compact (16B/pt: {thx,thy,thz,tlx,tly,tlz,n2h,n2l}); the 16-elem
// operand is rebuilt per-lane with 4 v_cndmask on khalf:
//   khalf0 dwords {d0,d1,d2,d0}, khalf1 {d1,d2,ONE.ONE,d3}.
// C/D layout: col=lane&31 (a), row=(reg&3)+8*(reg>>2)+4*(lane>>5) (b) ->
// min over b is in-lane fold + shfl_xor(32) khalf merge.
// No poison reliance: bcmp/gmin fully written before read.

#define NPTS 16384

typedef short s16x8 __attribute__((ext_vector_type(8)));
typedef unsigned int u32x4 __attribute__((ext_vector_type(4)));
typedef float f32x16 __attribute__((ext_vector_type(16)));

__device__ __forceinline__ unsigned short f2bf(float x) {
    unsigned u = __float_as_uint(x);
    u = u + 0x7FFFu + ((u >> 16) & 1u);   // RNE
    return (unsigned short)(u >> 16);
}
__device__ __forceinline__ float bf2f(unsigned short h) {
    return __uint_as_float((unsigned)h << 16);
}
__device__ __forceinline__ unsigned pk(unsigned short lo, unsigned short hi) {
    return (unsigned)lo | ((unsigned)hi << 16);
}

__global__ __launch_bounds__(256)
void cd_packb_kernel(const float* __restrict__ b,
                     u32x4* __restrict__ bcmp) {
    const int i = blockIdx.x * 256 + threadIdx.x;
    // ---- B compact: {thx,thy,thz,tlx,tly,tlz,n2h,n2l} (16B/pt)
    const float x = b[3 * i + 0], y = b[3 * i + 1], z = b[3 * i + 2];
    const float n2 = fmaf(x, x, fmaf(y, y, z * z));
    const unsigned short hx = f2bf(x), hy = f2bf(y), hz = f2bf(z);
    const unsigned short thx = f2bf(-2.0f * bf2f(hx));
    const unsigned short thy = f2bf(-2.0f * bf2f(hy));
    const unsigned short thz = f2bf(-2.0f * bf2f(hz));
    const unsigned short tlx = f2bf(-2.0f * (x - bf2f(hx)));
    const unsigned short tly = f2bf(-2.0f * (y - bf2f(hy)));
    const unsigned short tlz = f2bf(-2.0f * (z - bf2f(hz)));
    const unsigned short n2h = f2bf(n2), n2l = f2bf(n2 - bf2f(n2h));
    bcmp[i] = (u32x4){ pk(thx, thy), pk(thz, tlx), pk(tly, tlz), pk(n2h, n2l) };
}

__global__ __launch_bounds__(512, 4)   // cap VGPR<=128 -> 2 blocks/CU, 4 waves/SIMD
void cd_sweep_kernel(const float* __restrict__ a,
                     const u32x4* __restrict__ bcmp,
                     float* __restrict__ gmin) {
    __shared__ float red[8][32];
    const int tid   = threadIdx.x;
    const int lane  = tid & 63;
    const int wave  = tid >> 6;          // 0..7, owns b-range [wave*2048, +2048)
    const int col   = lane & 31;
    const int khalf = lane >> 5;

    // ---- A fragment built inline (R8 recipe, bit-identical to packed path) ----
    s16x8 af;
    {
        const int row = blockIdx.x * 32 + col;
        const float x = a[3 * row + 0];
        const float y = a[3 * row + 1];
        const float z = a[3 * row + 2];
        const float n2 = fmaf(x, x, fmaf(y, y, z * z));
        const unsigned short hx = f2bf(x), hy = f2bf(y), hz = f2bf(z);
        const unsigned short lx = f2bf(x - bf2f(hx));
        const unsigned short ly = f2bf(y - bf2f(hy));
        const unsigned short lz = f2bf(z - bf2f(hz));
        const unsigned short n2h = f2bf(n2);
        const unsigned short n2l = f2bf(n2 - bf2f(n2h));
        const unsigned short one = 0x3F80u;
        const s16x8 lo = {(short)hx, (short)hy, (short)hz, (short)hx,
                          (short)hy, (short)hz, (short)lx, (short)ly};
        const s16x8 hi = {(short)lz, (short)lx, (short)ly, (short)lz,
                          (short)n2h, (short)n2l, (short)one, (short)one};
        af = khalf ? hi : lo;
    }

    f32x16 best, zero;
    #pragma unroll
    for (int r = 0; r < 16; ++r) { best[r] = 3.4028235e38f; zero[r] = 0.0f; }

    const unsigned Kone = 0x3F803F80u;             // {1.0bf, 1.0bf}
    const u32x4* bp = bcmp + wave * 2048 + col;    // tile stride = 32 points

    #define EXPAND(e, d)                           \
        e[0] = khalf ? d[1] : d[0];                \
        e[1] = khalf ? d[2] : d[1];                \
        e[2] = khalf ? Kone : d[2];                \
        e[3] = khalf ? d[3] : d[0];

    for (int t = 0; t < 64; t += 4) {              // 64 tiles = 2048 b-pts
        // issue all 4 tile loads before any consume (vmcnt stagger)
        const u32x4 d0 = bp[(t + 0) * 32];
        const u32x4 d1 = bp[(t + 1) * 32];
        const u32x4 d2 = bp[(t + 2) * 32];
        const u32x4 d3 = bp[(t + 3) * 32];
        u32x4 e0, e1, e2, e3;                      // 4x v_cndmask each
        EXPAND(e0, d0) EXPAND(e1, d1) EXPAND(e2, d2) EXPAND(e3, d3)
        const f32x16 c0 = __builtin_amdgcn_mfma_f32_32x32x16_bf16(
            __builtin_bit_cast(s16x8, e0), af, zero, 0, 0, 0);
        const f32x16 c1 = __builtin_amdgcn_mfma_f32_32x32x16_bf16(
            __builtin_bit_cast(s16x8, e1), af, zero, 0, 0, 0);
        const f32x16 c2 = __builtin_amdgcn_mfma_f32_32x32x16_bf16(
            __builtin_bit_cast(s16x8, e2), af, zero, 0, 0, 0);
        const f32x16 c3 = __builtin_amdgcn_mfma_f32_32x32x16_bf16(
            __builtin_bit_cast(s16x8, e3), af, zero, 0, 0, 0);
        #pragma unroll
        for (int r = 0; r < 16; ++r) {
            best[r] = fminf(fminf(c0[r], c1[r]), best[r]);   // v_min3_f32
            best[r] = fminf(fminf(c2[r], c3[r]), best[r]);
        }
    }
    #undef EXPAND

    // in-lane fold over 16 b-rows; merge khalf halves from lane^32
    float m = best[0];
    #pragma unroll
    for (int r = 1; r < 16; ++r) m = fminf(m, best[r]);
    m = fminf(m, __shfl_xor(m, 32, 64));

    if (lane < 32) red[wave][col] = m;             // per-wave partial (its b-range)
    __syncthreads();
    if (tid < 32) {                                // final min across 8 waves
        float v = red[0][tid];
        #pragma unroll
        for (int w = 1; w < 8; ++w) v = fminf(v, red[w][tid]);
        gmin[blockIdx.x * 32 + tid] = fmaxf(v, 0.0f);   // plain store, no atomic
    }
}

__global__ __launch_bounds__(1024)
void cd_reduce_kernel(const float* __restrict__ gmin,
                      float* __restrict__ out) {
    __shared__ float red[16];
    const int tid = threadIdx.x;
    const float4* g4 = (const float4*)gmin;           // values already >= 0

    float s = 0.0f;
    #pragma unroll
    for (int i = tid; i < NPTS / 4; i += 1024) {
        const float4 v = g4[i];
        s += sqrtf(v.x) + sqrtf(v.y) + sqrtf(v.z) + sqrtf(v.w);
    }
    for (int off = 32; off > 0; off >>= 1)
        s += __shfl_down(s, off, 64);
    if ((tid & 63) == 0) red[tid >> 6] = s;
    __syncthreads();
    if (tid == 0) {
        float t = 0.0f;
        #pragma unroll
        for (int w = 0; w < 16; ++w) t += red[w];
        out[0] = t;                                   // single writer, no init
    }
}

extern "C" void kernel_launch(void* const* d_in, const int* in_sizes, int n_in,
                              void* d_out, int out_size, void* d_ws, size_t ws_size,
                              hipStream_t stream) {
    const float* a = (const float*)d_in[0];
    const float* b = (const float*)d_in[1];
    float* out = (float*)d_out;
    char* ws = (char*)d_ws;
    u32x4* bcmp = (u32x4*)(ws + 0);                 // 16384 * 16B = 256 KB
    float* gmin = (float*)(ws + 256 * 1024);        // 16384 * 4B  =  64 KB

    cd_packb_kernel<<<NPTS / 256, 256, 0, stream>>>(b, bcmp);
    cd_sweep_kernel<<<NPTS / 32, 512, 0, stream>>>(a, bcmp, gmin);
    cd_reduce_kernel<<<1, 1024, 0, stream>>>(gmin, out);
}

// Round 3
// 69.601 us; speedup vs baseline: 1.0388x; 1.0388x over previous
//
#include <hip/hip_runtime.h>
#include <math.h>

// Chamfer one-sided NN distance sum. N = M = 16384, D = 3, fp32 -> scalar fp32.
//
// R18: halve sweep load traffic with dual A-fragments per wave.
// History: R16 (ownership, 2-MFMA body) 70.9us; R17 (aexp drop + 4-MFMA body)
// 72.3us -- 4 live f32x16 accumulators blew the 128-VGPR cap of
// __launch_bounds__(512,4) -> serialize/spill, null result. The fill
// (~39.6us @ 85% HBM peak, harness ws poison) is fixed; the sweep is the only
// remaining term big enough to matter.
//
// Changes vs R16/R17 (bit-identical math, absmax 0.0 preserved):
//   1. Block owns 64 a-points (two 32-col fragments af0/af1); each B tile
//      operand e feeds TWO MFMAs -> B loads + cndmask expands HALVE
//      (32 loads/wave, 64MB unique L2 total) at constant min3 count
//      (512/wave = 1 op per 2 d^2 values, the VALU floor).
//   2. b-range split 2-ways: blockIdx.x = agroup*2+g; block sweeps
//      b in [g*8192, +8192), 1024 pts/wave. Merge via gmin[2][16384]
//      (plain stores); reduce folds min(g0,g1) elementwise -- fmin is
//      order-independent -> bit-exact vs single-range min.
//   3. Register discipline: only 2 c-vectors live at once (fold af0 pair
//      before computing af1 pair) -> ~114 VGPR <= 128, 4 waves/SIMD.
//   4. bcmp/gmin moved to the LAST 512KB of ws: the tail of the 256MiB
//      poison-fill is L2-resident -> pack writes hit dirty L2 lines.
//
// MFMA formulation (R8, absmax 0.0 verified): d2(i,j) = |a|^2+|b|^2-2a.b via
// split-bf16, one v_mfma_f32_32x32x16_bf16 per 32x32 tile:
//   A[i][k] = [ahx,ahy,ahz, ahx,ahy,ahz, alx,aly,alz, alx,aly,alz, a2h,a2l,1,1]
//   B[j][k] = [-2bh(3),-2bl(3), -2bh(3),-2bl(3), 1,1, b2h,b2l]
// B stored compact (16B/pt: {thx,thy,thz,tlx,tly,tlz,n2h,n2l}); 16-elem
// operand rebuilt per-lane with 4 v_cndmask on khalf:
//   khalf0 dwords {d0,d1,d2,d0}, khalf1 {d1,d2,ONE.ONE,d3}.
// C/D layout: col=lane&31 (a), row=(reg&3)+8*(reg>>2)+4*(lane>>5) (b) ->
// min over b is in-lane fold + shfl_xor(32) khalf merge.
// No poison reliance: bcmp/gmin fully written before read.

#define NPTS 16384

typedef short s16x8 __attribute__((ext_vector_type(8)));
typedef unsigned int u32x4 __attribute__((ext_vector_type(4)));
typedef float f32x16 __attribute__((ext_vector_type(16)));

__device__ __forceinline__ unsigned short f2bf(float x) {
    unsigned u = __float_as_uint(x);
    u = u + 0x7FFFu + ((u >> 16) & 1u);   // RNE
    return (unsigned short)(u >> 16);
}
__device__ __forceinline__ float bf2f(unsigned short h) {
    return __uint_as_float((unsigned)h << 16);
}
__device__ __forceinline__ unsigned pk(unsigned short lo, unsigned short hi) {
    return (unsigned)lo | ((unsigned)hi << 16);
}

__global__ __launch_bounds__(256)
void cd_packb_kernel(const float* __restrict__ b,
                     u32x4* __restrict__ bcmp) {
    const int i = blockIdx.x * 256 + threadIdx.x;
    // ---- B compact: {thx,thy,thz,tlx,tly,tlz,n2h,n2l} (16B/pt)
    const float x = b[3 * i + 0], y = b[3 * i + 1], z = b[3 * i + 2];
    const float n2 = fmaf(x, x, fmaf(y, y, z * z));
    const unsigned short hx = f2bf(x), hy = f2bf(y), hz = f2bf(z);
    const unsigned short thx = f2bf(-2.0f * bf2f(hx));
    const unsigned short thy = f2bf(-2.0f * bf2f(hy));
    const unsigned short thz = f2bf(-2.0f * bf2f(hz));
    const unsigned short tlx = f2bf(-2.0f * (x - bf2f(hx)));
    const unsigned short tly = f2bf(-2.0f * (y - bf2f(hy)));
    const unsigned short tlz = f2bf(-2.0f * (z - bf2f(hz)));
    const unsigned short n2h = f2bf(n2), n2l = f2bf(n2 - bf2f(n2h));
    bcmp[i] = (u32x4){ pk(thx, thy), pk(thz, tlx), pk(tly, tlz), pk(n2h, n2l) };
}

__device__ __forceinline__ s16x8 make_afrag(const float* __restrict__ a,
                                            int row, int khalf) {
    const float x = a[3 * row + 0];
    const float y = a[3 * row + 1];
    const float z = a[3 * row + 2];
    const float n2 = fmaf(x, x, fmaf(y, y, z * z));
    const unsigned short hx = f2bf(x), hy = f2bf(y), hz = f2bf(z);
    const unsigned short lx = f2bf(x - bf2f(hx));
    const unsigned short ly = f2bf(y - bf2f(hy));
    const unsigned short lz = f2bf(z - bf2f(hz));
    const unsigned short n2h = f2bf(n2);
    const unsigned short n2l = f2bf(n2 - bf2f(n2h));
    const unsigned short one = 0x3F80u;
    const s16x8 lo = {(short)hx, (short)hy, (short)hz, (short)hx,
                      (short)hy, (short)hz, (short)lx, (short)ly};
    const s16x8 hi = {(short)lz, (short)lx, (short)ly, (short)lz,
                      (short)n2h, (short)n2l, (short)one, (short)one};
    return khalf ? hi : lo;
}

__global__ __launch_bounds__(512, 4)   // <=128 VGPR -> 4 waves/SIMD
void cd_sweep_kernel(const float* __restrict__ a,
                     const u32x4* __restrict__ bcmp,
                     float* __restrict__ gmin) {
    __shared__ float red[8][64];
    const int tid   = threadIdx.x;
    const int lane  = tid & 63;
    const int wave  = tid >> 6;          // 0..7
    const int col   = lane & 31;
    const int khalf = lane >> 5;
    const int agroup = blockIdx.x >> 1;  // 256 groups of 64 a-points
    const int g      = blockIdx.x & 1;   // b-range half

    // two A fragments per wave: cols agroup*64+col and agroup*64+32+col
    const s16x8 af0 = make_afrag(a, agroup * 64 + col, khalf);
    const s16x8 af1 = make_afrag(a, agroup * 64 + 32 + col, khalf);

    f32x16 best0, best1, zero;
    #pragma unroll
    for (int r = 0; r < 16; ++r) {
        best0[r] = 3.4028235e38f; best1[r] = 3.4028235e38f; zero[r] = 0.0f;
    }

    const unsigned Kone = 0x3F803F80u;   // {1.0bf, 1.0bf}
    // wave sweeps 1024 b-pts = 32 tiles in [g*8192 + wave*1024, +1024)
    const u32x4* bp = bcmp + g * 8192 + wave * 1024 + col;

    #define EXPAND(e, d)                           \
        e[0] = khalf ? d[1] : d[0];                \
        e[1] = khalf ? d[2] : d[1];                \
        e[2] = khalf ? Kone : d[2];                \
        e[3] = khalf ? d[3] : d[0];

    #pragma unroll 2
    for (int t = 0; t < 32; t += 2) {
        const u32x4 d0 = bp[(t + 0) * 32];         // both loads issued first
        const u32x4 d1 = bp[(t + 1) * 32];
        u32x4 e0, e1;                               // 4x v_cndmask each
        EXPAND(e0, d0) EXPAND(e1, d1)
        {   // af0 pair folded before af1 pair -> only 2 c-vectors live
            const f32x16 c0 = __builtin_amdgcn_mfma_f32_32x32x16_bf16(
                __builtin_bit_cast(s16x8, e0), af0, zero, 0, 0, 0);
            const f32x16 c1 = __builtin_amdgcn_mfma_f32_32x32x16_bf16(
                __builtin_bit_cast(s16x8, e1), af0, zero, 0, 0, 0);
            #pragma unroll
            for (int r = 0; r < 16; ++r)
                best0[r] = fminf(fminf(c0[r], c1[r]), best0[r]);   // v_min3_f32
        }
        {
            const f32x16 c0 = __builtin_amdgcn_mfma_f32_32x32x16_bf16(
                __builtin_bit_cast(s16x8, e0), af1, zero, 0, 0, 0);
            const f32x16 c1 = __builtin_amdgcn_mfma_f32_32x32x16_bf16(
                __builtin_bit_cast(s16x8, e1), af1, zero, 0, 0, 0);
            #pragma unroll
            for (int r = 0; r < 16; ++r)
                best1[r] = fminf(fminf(c0[r], c1[r]), best1[r]);
        }
    }
    #undef EXPAND

    // in-lane fold over 16 b-rows; merge khalf halves from lane^32
    float m0 = best0[0], m1 = best1[0];
    #pragma unroll
    for (int r = 1; r < 16; ++r) {
        m0 = fminf(m0, best0[r]);
        m1 = fminf(m1, best1[r]);
    }
    m0 = fminf(m0, __shfl_xor(m0, 32, 64));
    m1 = fminf(m1, __shfl_xor(m1, 32, 64));

    if (lane < 32) {
        red[wave][col]      = m0;        // per-wave partial (its 1024-pt range)
        red[wave][col + 32] = m1;
    }
    __syncthreads();
    if (tid < 64) {                      // min across 8 waves -> plain store
        float v = red[0][tid];
        #pragma unroll
        for (int w = 1; w < 8; ++w) v = fminf(v, red[w][tid]);
        gmin[g * NPTS + agroup * 64 + tid] = fmaxf(v, 0.0f);
    }
}

__global__ __launch_bounds__(1024)
void cd_reduce_kernel(const float* __restrict__ gmin,
                      float* __restrict__ out) {
    __shared__ float red[16];
    const int tid = threadIdx.x;
    const float4* g0 = (const float4*)gmin;           // b-half 0, clamped >= 0
    const float4* g1 = (const float4*)(gmin + NPTS);  // b-half 1

    float s = 0.0f;
    #pragma unroll
    for (int i = tid; i < NPTS / 4; i += 1024) {
        const float4 u = g0[i];
        const float4 v = g1[i];
        s += sqrtf(fminf(u.x, v.x)) + sqrtf(fminf(u.y, v.y)) +
             sqrtf(fminf(u.z, v.z)) + sqrtf(fminf(u.w, v.w));
    }
    for (int off = 32; off > 0; off >>= 1)
        s += __shfl_down(s, off, 64);
    if ((tid & 63) == 0) red[tid >> 6] = s;
    __syncthreads();
    if (tid == 0) {
        float t = 0.0f;
        #pragma unroll
        for (int w = 0; w < 16; ++w) t += red[w];
        out[0] = t;                                   // single writer, no init
    }
}

extern "C" void kernel_launch(void* const* d_in, const int* in_sizes, int n_in,
                              void* d_out, int out_size, void* d_ws, size_t ws_size,
                              hipStream_t stream) {
    const float* a = (const float*)d_in[0];
    const float* b = (const float*)d_in[1];
    float* out = (float*)d_out;
    char* ws = (char*)d_ws;
    // Place buffers in the LAST 512KB of ws: the tail of the harness's 256MiB
    // poison-fill is still L2-resident, so pack writes hit dirty L2 lines.
    const size_t tail = (ws_size >= (1u << 20)) ? (ws_size - (512u << 10)) : 0u;
    u32x4* bcmp = (u32x4*)(ws + tail);                // 16384 * 16B = 256 KB
    float* gmin = (float*)(ws + tail + 256 * 1024);   // 2 * 16384 * 4B = 128 KB

    cd_packb_kernel<<<NPTS / 256, 256, 0, stream>>>(b, bcmp);
    cd_sweep_kernel<<<NPTS / 32, 512, 0, stream>>>(a, bcmp, gmin);
    cd_reduce_kernel<<<1, 1024, 0, stream>>>(gmin, out);
}